// Round 11
// baseline (109.905 us; speedup 1.0000x reference)
//
#include <hip/hip_runtime.h>

#define N_IMG 32
#define H_IMG 224
#define W_IMG 224

// Unified unit space, heavy scales first.
// s>=2: one output per unit; s=1: two outputs (vec2) per unit.
#define U16 6272      // 32*14*14
#define U8  25088     // 32*28*28
#define U4  100352    // 32*56*56
#define U2  401408    // 32*112*112
#define U1V 802816    // 32*224*112 (vec2)  [R10 bug: was 401408]
#define O8  (U16)
#define O4  (O8 + U8)      // 31360
#define O2  (O4 + U4)      // 131712
#define O1  (O2 + U2)      // 533120
#define NTOT (O1 + U1V)    // 1335936

#define NBLK 2048
#define NTHREADS (NBLK * 256)  // 524288: whole grid resident at 8 blocks/CU

__device__ __forceinline__ int reflect_idx(int i, int n) {
    if (i < 0) return -i;
    if (i >= n) return 2 * n - 2 - i;
    return i;
}

// bin = floor(atan2(gx,gy)/pi*9) mod 9 without atan2: direction-only sector count.
__device__ __forceinline__ int bin_from_g(float gx, float gy) {
    float u = gx * __builtin_copysignf(1.0f, gy);
    float w = __builtin_fabsf(gy);
    const float T[9] = {-5.6712818f, -1.7320508f, -0.83909963f, -0.36397023f,
                        0.0f, 0.36397023f, 0.83909963f, 1.7320508f, 5.6712818f};
    int c = 0;
    #pragma unroll
    for (int k = 0; k < 9; ++k) c += (u >= T[k] * w) ? 1 : 0;
    int b = c + 4;
    return (b >= 9) ? b - 9 : b;
}

// ---------------- s=1, two outputs per unit ----------------
__device__ __forceinline__ float s1_unit(int r,
    const float* __restrict__ imgs, const float* __restrict__ mask,
    const float* __restrict__ pred,
    const float* spwT, const float* spb, const float* sA, const float* sB,
    float Cc, float& mout)
{
    constexpr int WsV = W_IMG / 2;   // 112
    int jv = r % WsV;
    int t  = r / WsV;
    int i  = t % H_IMG;
    int n  = t / H_IMG;
    int j0 = jv * 2;

    constexpr size_t cstride = (size_t)H_IMG * W_IMG;
    float2 mv = *(const float2*)(mask + (size_t)n * cstride + (size_t)i * W_IMG + j0);

    int y0 = reflect_idx(i - 1, H_IMG), y2 = reflect_idx(i + 1, H_IMG);
    int xl = reflect_idx(j0 - 1, W_IMG);
    int xr = reflect_idx(j0 + 2, W_IMG);

    float d2[2] = {0.0f, 0.0f};
    #pragma unroll
    for (int c = 0; c < 3; ++c) {
        const float* im = imgs + (size_t)(n * 3 + c) * cstride;
        const float* q0 = im + (size_t)y0 * W_IMG;
        const float* q1 = im + (size_t)i  * W_IMG;
        const float* q2 = im + (size_t)y2 * W_IMG;

        // img loads first (oldest in queue -> sobel waits only on these)
        float r0[4], r1[4], r2[4];
        float2 f;
        r0[0] = q0[xl]; f = *(const float2*)(q0 + j0); r0[1] = f.x; r0[2] = f.y; r0[3] = q0[xr];
        r1[0] = q1[xl]; f = *(const float2*)(q1 + j0); r1[1] = f.x; r1[2] = f.y; r1[3] = q1[xr];
        r2[0] = q2[xl]; f = *(const float2*)(q2 + j0); r2[1] = f.x; r2[2] = f.y; r2[3] = q2[xr];

        // stage 9 float2 preds (fly under the sobel math)
        const float* pr = pred + ((size_t)(n * 27 + c * 9) * H_IMG + i) * W_IMG + j0;
        float2 p[9];
        #pragma unroll
        for (int o = 0; o < 9; ++o) p[o] = *(const float2*)(pr + o * cstride);

        #pragma unroll
        for (int v = 0; v < 2; ++v) {
            float gx = (r0[v] - r0[v + 2]) + 2.0f * (r1[v] - r1[v + 2]) + (r2[v] - r2[v + 2]);
            float gy = (r0[v] - r2[v]) + 2.0f * (r0[v + 1] - r2[v + 1]) + (r0[v + 2] - r2[v + 2]);
            float mag = sqrtf(gx * gx + gy * gy);
            int bn = bin_from_g(gx, gy);
            float nrm2 = fmaf(mag, fmaf(mag, sA[bn], 2.0f * sB[bn]), Cc);
            float inv = 1.0f / fmaxf(sqrtf(nrm2), 1e-12f);
            #pragma unroll
            for (int o = 0; o < 9; ++o) {
                float h = fmaf(spwT[bn * 9 + o], mag, spb[o]) * inv;
                float pv = (v == 0) ? p[o].x : p[o].y;
                float dd = pv - h;
                d2[v] += dd * dd;
            }
        }
    }

    mout = mv.x + mv.y;   // sum over s=1 == sum(mask)
    return (mv.x * d2[0] + mv.y * d2[1]) * (1.0f / 27.0f);
}

// ---------------- generic S>=2, one output per unit ----------------
template <int S>
__device__ __forceinline__ float scale_unit(int r,
    const float* __restrict__ imgs, const float* __restrict__ mask,
    const float* __restrict__ pred,
    const float* spwT, const float* spb, const float* sA, const float* sB,
    float Cc)
{
    constexpr int Hs = H_IMG / S, Ws = W_IMG / S;
    int j = r % Ws;
    int t = r / Ws;
    int i = t % Hs;
    int n = t / Hs;

    // ---- mask pooling: fully unrolled, independent loads ----
    float M;
    const float* mbase = mask + (size_t)n * H_IMG * W_IMG + (size_t)(i * S) * W_IMG + j * S;
    if constexpr (S == 2) {
        float2 a = *(const float2*)(mbase);
        float2 b = *(const float2*)(mbase + W_IMG);
        M = (a.x + a.y + b.x + b.y) * 0.25f;
    } else {
        float msum = 0.0f;
        #pragma unroll
        for (int a = 0; a < S; ++a) {
            const float* mr = mbase + (size_t)a * W_IMG;
            #pragma unroll
            for (int q = 0; q < S / 4; ++q) {
                float4 fv = *(const float4*)(mr + q * 4);
                msum += (fv.x + fv.y) + (fv.z + fv.w);
            }
        }
        M = msum * (1.0f / (float)(S * S));
    }

    int y = i * S, x = j * S;
    int y0 = reflect_idx(y - 1, H_IMG), y2 = reflect_idx(y + 1, H_IMG);
    int x0 = reflect_idx(x - 1, W_IMG), x2 = reflect_idx(x + 1, W_IMG);
    constexpr size_t cstride = (size_t)Hs * Ws;

    float d2 = 0.0f;
    #pragma unroll
    for (int c = 0; c < 3; ++c) {
        const float* im = imgs + (size_t)(n * 3 + c) * H_IMG * W_IMG;
        const float* q0 = im + (size_t)y0 * W_IMG;
        const float* q1 = im + (size_t)y  * W_IMG;
        const float* q2 = im + (size_t)y2 * W_IMG;
        float p00 = q0[x0], p01 = q0[x], p02 = q0[x2];
        float p10 = q1[x0],             p12 = q1[x2];
        float p20 = q2[x0], p21 = q2[x], p22 = q2[x2];

        const float* pr = pred + ((size_t)(n * 27 + c * 9) * Hs + i) * Ws + j;
        float p[9];
        #pragma unroll
        for (int o = 0; o < 9; ++o) p[o] = pr[o * cstride];

        float gx = (p00 - p02) + 2.0f * (p10 - p12) + (p20 - p22);
        float gy = (p00 - p20) + 2.0f * (p01 - p21) + (p02 - p22);
        float mag = sqrtf(gx * gx + gy * gy);
        int bn = bin_from_g(gx, gy);
        float nrm2 = fmaf(mag, fmaf(mag, sA[bn], 2.0f * sB[bn]), Cc);
        float inv = 1.0f / fmaxf(sqrtf(nrm2), 1e-12f);

        #pragma unroll
        for (int o = 0; o < 9; ++o) {
            float h = fmaf(spwT[bn * 9 + o], mag, spb[o]) * inv;
            float dd = p[o] - h;
            d2 += dd * dd;
        }
    }

    return M * d2 * (1.0f / 27.0f);
}

__global__ void __launch_bounds__(256) fused_kernel(
    const float* __restrict__ imgs, const float* __restrict__ mask,
    const float* __restrict__ pred0, const float* __restrict__ pred1,
    const float* __restrict__ pred2, const float* __restrict__ pred3,
    const float* __restrict__ pred4,
    const float* __restrict__ pw0, const float* __restrict__ pw1,
    const float* __restrict__ pw2, const float* __restrict__ pw3,
    const float* __restrict__ pw4,
    const float* __restrict__ pb0, const float* __restrict__ pb1,
    const float* __restrict__ pb2, const float* __restrict__ pb3,
    const float* __restrict__ pb4,
    double* __restrict__ pl, double* __restrict__ pm)
{
    // tables for all 5 scales, built once per (persistent) block
    __shared__ float spwT[5][81];   // spwT[k][b*9+o] = pw_k[o*9+b]
    __shared__ float spb[5][9];
    __shared__ float sA[5][9], sB[5][9], sC[5];

    const float* pws[5] = {pw0, pw1, pw2, pw3, pw4};
    const float* pbs[5] = {pb0, pb1, pb2, pb3, pb4};
    #pragma unroll
    for (int k = 0; k < 5; ++k) {
        if (threadIdx.x < 81) {
            int o = threadIdx.x / 9, b = threadIdx.x % 9;
            spwT[k][b * 9 + o] = pws[k][threadIdx.x];
        }
        if (threadIdx.x < 9) spb[k][threadIdx.x] = pbs[k][threadIdx.x];
    }
    __syncthreads();
    #pragma unroll
    for (int k = 0; k < 5; ++k) {
        if (threadIdx.x < 9) {
            float A = 0.0f, B = 0.0f;
            #pragma unroll
            for (int o = 0; o < 9; ++o) {
                float w = spwT[k][threadIdx.x * 9 + o];
                A += w * w;
                B += w * spb[k][o];
            }
            sA[k][threadIdx.x] = A;
            sB[k][threadIdx.x] = B;
            if (threadIdx.x == 0) {
                float Cv = 0.0f;
                #pragma unroll
                for (int o = 0; o < 9; ++o) Cv += spb[k][o] * spb[k][o];
                sC[k] = Cv;
            }
        }
    }
    __syncthreads();

    float lacc = 0.0f, macc = 0.0f;
    for (int u = blockIdx.x * 256 + (int)threadIdx.x; u < NTOT; u += NTHREADS) {
        if (u < O8) {
            lacc += 256.0f * scale_unit<16>(u, imgs, mask, pred0,
                        spwT[0], spb[0], sA[0], sB[0], sC[0]);
        } else if (u < O4) {
            lacc += 64.0f * scale_unit<8>(u - O8, imgs, mask, pred1,
                        spwT[1], spb[1], sA[1], sB[1], sC[1]);
        } else if (u < O2) {
            lacc += 16.0f * scale_unit<4>(u - O4, imgs, mask, pred2,
                        spwT[2], spb[2], sA[2], sB[2], sC[2]);
        } else if (u < O1) {
            lacc += 4.0f * scale_unit<2>(u - O2, imgs, mask, pred3,
                        spwT[3], spb[3], sA[3], sB[3], sC[3]);
        } else {
            float m;
            lacc += s1_unit(u - O1, imgs, mask, pred4,
                        spwT[4], spb[4], sA[4], sB[4], sC[4], m);
            macc += m;
        }
    }

    #pragma unroll
    for (int off = 32; off > 0; off >>= 1) {
        lacc += __shfl_down(lacc, off, 64);
        macc += __shfl_down(macc, off, 64);
    }
    __shared__ float s1s[4], s2s[4];
    int lane = threadIdx.x & 63, wid = threadIdx.x >> 6;
    if (lane == 0) { s1s[wid] = lacc; s2s[wid] = macc; }
    __syncthreads();
    if (threadIdx.x == 0) {
        pl[blockIdx.x] = (double)(s1s[0] + s1s[1] + s1s[2] + s1s[3]);
        pm[blockIdx.x] = (double)(s2s[0] + s2s[1] + s2s[2] + s2s[3]);
    }
}

__global__ void __launch_bounds__(256) finalize_kernel(
    const double* __restrict__ pl, const double* __restrict__ pm,
    float* __restrict__ out)
{
    double l = 0.0, m = 0.0;
    for (int idx = threadIdx.x; idx < NBLK; idx += 256) {
        l += pl[idx];
        m += pm[idx];
    }
    #pragma unroll
    for (int off = 32; off > 0; off >>= 1) {
        l += __shfl_down(l, off, 64);
        m += __shfl_down(m, off, 64);
    }
    __shared__ double sl[4], sm[4];
    int lane = threadIdx.x & 63, wid = threadIdx.x >> 6;
    if (lane == 0) { sl[wid] = l; sm[wid] = m; }
    __syncthreads();
    if (threadIdx.x == 0)
        out[0] = (float)((sl[0] + sl[1] + sl[2] + sl[3]) / (sm[0] + sm[1] + sm[2] + sm[3]));
}

extern "C" void kernel_launch(void* const* d_in, const int* in_sizes, int n_in,
                              void* d_out, int out_size, void* d_ws, size_t ws_size,
                              hipStream_t stream) {
    (void)in_sizes; (void)n_in; (void)out_size; (void)ws_size;
    const float* imgs = (const float*)d_in[0];
    const float* mask = (const float*)d_in[1];
    const float* pred[5];
    const float* pw[5];
    const float* pb[5];
    for (int k = 0; k < 5; ++k) {
        pred[k] = (const float*)d_in[2 + 3 * k];
        pw[k]   = (const float*)d_in[3 + 3 * k];
        pb[k]   = (const float*)d_in[4 + 3 * k];
    }
    double* pl = (double*)d_ws;
    double* pm = pl + NBLK;

    fused_kernel<<<NBLK, 256, 0, stream>>>(
        imgs, mask,
        pred[0], pred[1], pred[2], pred[3], pred[4],
        pw[0], pw[1], pw[2], pw[3], pw[4],
        pb[0], pb[1], pb[2], pb[3], pb[4],
        pl, pm);
    finalize_kernel<<<1, 256, 0, stream>>>(pl, pm, (float*)d_out);
}

// Round 12
// 105.165 us; speedup vs baseline: 1.0451x; 1.0451x over previous
//
#include <hip/hip_runtime.h>

#define N_IMG 32
#define H_IMG 224
#define W_IMG 224
#define HW 50176            // 224*224

// 512-thread blocks. Heavy scales first (one output per thread, VEC=1):
// S=16: [0, 13)      6272 units
// S=8 : [13, 62)     25088
// S=4 : [62, 258)    100352
// S=2 : [258, 1042)  401408
// s=1 slabs: [1042, 2834)  32 imgs * 56 slabs (4 rows each)
#define BS16_END 13
#define BS8_END 62
#define BS4_END 258
#define BS2_END 1042
#define NBLK_TOTAL 2834
#define NTHR 512

__device__ __forceinline__ int reflect_idx(int i, int n) {
    if (i < 0) return -i;
    if (i >= n) return 2 * n - 2 - i;
    return i;
}

// bin = floor(atan2(gx,gy)/pi*9) mod 9 without atan2: direction-only sector count.
__device__ __forceinline__ int bin_from_g(float gx, float gy) {
    float u = gx * __builtin_copysignf(1.0f, gy);
    float w = __builtin_fabsf(gy);
    const float T[9] = {-5.6712818f, -1.7320508f, -0.83909963f, -0.36397023f,
                        0.0f, 0.36397023f, 0.83909963f, 1.7320508f, 5.6712818f};
    int c = 0;
    #pragma unroll
    for (int k = 0; k < 9; ++k) c += (u >= T[k] * w) ? 1 : 0;
    int b = c + 4;
    return (b >= 9) ? b - 9 : b;
}

// ---------------- generic S>=2, one output per thread ----------------
template <int S>
__device__ __forceinline__ float scale_unit(int vt,
    const float* __restrict__ imgs, const float* __restrict__ mask,
    const float* __restrict__ pred,
    const float* spwT, const float* spb, const float* sA, const float* sB,
    float Cc)
{
    constexpr int Hs = H_IMG / S, Ws = W_IMG / S;
    if (vt >= N_IMG * Hs * Ws) return 0.0f;
    int j = vt % Ws;
    int t = vt / Ws;
    int i = t % Hs;
    int n = t / Hs;

    float M;
    const float* mbase = mask + (size_t)n * HW + (size_t)(i * S) * W_IMG + j * S;
    if constexpr (S == 2) {
        float2 a = *(const float2*)(mbase);
        float2 b = *(const float2*)(mbase + W_IMG);
        M = (a.x + a.y + b.x + b.y) * 0.25f;
    } else {
        float msum = 0.0f;
        #pragma unroll
        for (int a = 0; a < S; ++a) {
            const float* mr = mbase + (size_t)a * W_IMG;
            #pragma unroll
            for (int q = 0; q < S / 4; ++q) {
                float4 fv = *(const float4*)(mr + q * 4);
                msum += (fv.x + fv.y) + (fv.z + fv.w);
            }
        }
        M = msum * (1.0f / (float)(S * S));
    }

    int y = i * S, x = j * S;
    int y0 = reflect_idx(y - 1, H_IMG), y2 = reflect_idx(y + 1, H_IMG);
    int x0 = reflect_idx(x - 1, W_IMG), x2 = reflect_idx(x + 1, W_IMG);
    constexpr size_t cstride = (size_t)Hs * Ws;

    float d2 = 0.0f;
    #pragma unroll
    for (int c = 0; c < 3; ++c) {
        const float* im = imgs + (size_t)(n * 3 + c) * HW;
        const float* q0 = im + (size_t)y0 * W_IMG;
        const float* q1 = im + (size_t)y  * W_IMG;
        const float* q2 = im + (size_t)y2 * W_IMG;
        float p00 = q0[x0], p01 = q0[x], p02 = q0[x2];
        float p10 = q1[x0],             p12 = q1[x2];
        float p20 = q2[x0], p21 = q2[x], p22 = q2[x2];

        const float* pr = pred + ((size_t)(n * 27 + c * 9) * Hs + i) * Ws + j;
        float p[9];
        #pragma unroll
        for (int o = 0; o < 9; ++o) p[o] = pr[o * cstride];

        float gx = (p00 - p02) + 2.0f * (p10 - p12) + (p20 - p22);
        float gy = (p00 - p20) + 2.0f * (p01 - p21) + (p02 - p22);
        float mag = sqrtf(gx * gx + gy * gy);
        int bn = bin_from_g(gx, gy);
        float nrm2 = fmaf(mag, fmaf(mag, sA[bn], 2.0f * sB[bn]), Cc);
        float inv = 1.0f / fmaxf(sqrtf(nrm2), 1e-12f);

        #pragma unroll
        for (int o = 0; o < 9; ++o) {
            float h = fmaf(spwT[bn * 9 + o], mag, spb[o]) * inv;
            float dd = p[o] - h;
            d2 += dd * dd;
        }
    }

    return M * d2 * (1.0f / 27.0f);
}

__global__ void __launch_bounds__(NTHR) fused_kernel(
    const float* __restrict__ imgs, const float* __restrict__ mask,
    const float* __restrict__ pred0, const float* __restrict__ pred1,
    const float* __restrict__ pred2, const float* __restrict__ pred3,
    const float* __restrict__ pred4,
    const float* __restrict__ pw0, const float* __restrict__ pw1,
    const float* __restrict__ pw2, const float* __restrict__ pw3,
    const float* __restrict__ pw4,
    const float* __restrict__ pb0, const float* __restrict__ pb1,
    const float* __restrict__ pb2, const float* __restrict__ pb3,
    const float* __restrict__ pb4,
    double* __restrict__ pl, double* __restrict__ pm)
{
    // per-block scale tables
    __shared__ float spwT[81];   // spwT[b*9+o] = pw[o*9+b]
    __shared__ float spb[9];
    __shared__ float sA[9], sB[9], sC[1];
    // s=1 slab staging (SoA by e: index ((c*4+r)*4+e)*56 + jv)
    __shared__ float sminv[3 * 4 * 4 * 56];          // mag*inv
    __shared__ float sinvv[3 * 4 * 4 * 56];          // inv
    __shared__ unsigned char sbinv[3 * 4 * 4 * 56];  // bin
    __shared__ float smask[4 * 4 * 56];              // mask slab, (r*4+e)*56+jv

    int bid = blockIdx.x;
    int tid = (int)threadIdx.x;

    const float* pw;  const float* pb;
    if (bid < BS16_END)      { pw = pw0; pb = pb0; }
    else if (bid < BS8_END)  { pw = pw1; pb = pb1; }
    else if (bid < BS4_END)  { pw = pw2; pb = pb2; }
    else if (bid < BS2_END)  { pw = pw3; pb = pb3; }
    else                     { pw = pw4; pb = pb4; }

    if (tid < 81) {
        int o = tid / 9, b = tid % 9;
        spwT[b * 9 + o] = pw[tid];
    }
    if (tid < 9) spb[tid] = pb[tid];
    __syncthreads();
    if (tid < 9) {
        float A = 0.0f, B = 0.0f;
        #pragma unroll
        for (int o = 0; o < 9; ++o) {
            float w = spwT[tid * 9 + o];
            A += w * w;
            B += w * spb[o];
        }
        sA[tid] = A;
        sB[tid] = B;
        if (tid == 0) {
            float Cv = 0.0f;
            #pragma unroll
            for (int o = 0; o < 9; ++o) Cv += spb[o] * spb[o];
            sC[0] = Cv;
        }
    }
    __syncthreads();
    float Cc = sC[0];

    float lacc = 0.0f, macc = 0.0f;

    if (bid < BS2_END) {
        // -------- S >= 2 paths --------
        if (bid < BS16_END)
            lacc = 256.0f * scale_unit<16>(bid * NTHR + tid, imgs, mask, pred0, spwT, spb, sA, sB, Cc);
        else if (bid < BS8_END)
            lacc = 64.0f * scale_unit<8>((bid - BS16_END) * NTHR + tid, imgs, mask, pred1, spwT, spb, sA, sB, Cc);
        else if (bid < BS4_END)
            lacc = 16.0f * scale_unit<4>((bid - BS8_END) * NTHR + tid, imgs, mask, pred2, spwT, spb, sA, sB, Cc);
        else
            lacc = 4.0f * scale_unit<2>((bid - BS4_END) * NTHR + tid, imgs, mask, pred3, spwT, spb, sA, sB, Cc);
    } else {
        // -------- s=1 slab: phase 1 (HOG -> LDS), phase 2 (stream preds) ----
        int rel  = bid - BS2_END;
        int n    = rel / 56;
        int slab = rel % 56;
        int r0   = slab * 4;

        // phase 1: 672 vec4-stencil units = 3 channels * 4 rows * 56 jv
        for (int u = tid; u < 672; u += NTHR) {
            int c   = u / 224;
            int rem = u % 224;
            int r   = rem / 56;
            int jv  = rem % 56;
            int j0  = jv * 4;
            int gi  = r0 + r;
            int y0 = reflect_idx(gi - 1, H_IMG), y2 = reflect_idx(gi + 1, H_IMG);
            int xl = reflect_idx(j0 - 1, W_IMG), xr = reflect_idx(j0 + 4, W_IMG);
            const float* im = imgs + (size_t)(n * 3 + c) * HW;
            const float* q0 = im + (size_t)y0 * W_IMG;
            const float* q1 = im + (size_t)gi * W_IMG;
            const float* q2 = im + (size_t)y2 * W_IMG;
            float a0[6], a1[6], a2[6];
            float4 f;
            a0[0] = q0[xl]; f = *(const float4*)(q0 + j0);
            a0[1] = f.x; a0[2] = f.y; a0[3] = f.z; a0[4] = f.w; a0[5] = q0[xr];
            a1[0] = q1[xl]; f = *(const float4*)(q1 + j0);
            a1[1] = f.x; a1[2] = f.y; a1[3] = f.z; a1[4] = f.w; a1[5] = q1[xr];
            a2[0] = q2[xl]; f = *(const float4*)(q2 + j0);
            a2[1] = f.x; a2[2] = f.y; a2[3] = f.z; a2[4] = f.w; a2[5] = q2[xr];
            int base = (c * 4 + r) * 4;
            #pragma unroll
            for (int e = 0; e < 4; ++e) {
                float gx = (a0[e] - a0[e + 2]) + 2.0f * (a1[e] - a1[e + 2]) + (a2[e] - a2[e + 2]);
                float gy = (a0[e] - a2[e]) + 2.0f * (a0[e + 1] - a2[e + 1]) + (a0[e + 2] - a2[e + 2]);
                float mag = sqrtf(gx * gx + gy * gy);
                int bn = bin_from_g(gx, gy);
                float nrm2 = fmaf(mag, fmaf(mag, sA[bn], 2.0f * sB[bn]), Cc);
                float inv = 1.0f / fmaxf(sqrtf(nrm2), 1e-12f);
                int li = (base + e) * 56 + jv;
                sminv[li] = mag * inv;
                sinvv[li] = inv;
                sbinv[li] = (unsigned char)bn;
            }
        }
        // mask slab staging + mask sum (each element exactly once)
        if (tid < 224) {
            int r = tid / 56, jv = tid % 56;
            const float* mb = mask + (size_t)n * HW + (size_t)r0 * W_IMG + tid * 4;
            float4 mv = *(const float4*)mb;
            float me[4] = {mv.x, mv.y, mv.z, mv.w};
            #pragma unroll
            for (int e = 0; e < 4; ++e) smask[(r * 4 + e) * 56 + jv] = me[e];
            macc = (me[0] + me[1]) + (me[2] + me[3]);
        }
        __syncthreads();

        // phase 2: stream 27 contiguous plane-slabs (27*224 float4 units)
        const float* pbase = pred4 + (size_t)(n * 27) * HW + (size_t)r0 * W_IMG;
        int idx = tid;
        float4 cur;
        if (idx < 6048) {
            int p = idx / 224, off = idx % 224;
            cur = *(const float4*)(pbase + (size_t)p * HW + off * 4);
        }
        while (idx < 6048) {
            int nidx = idx + NTHR;
            float4 nxt;
            if (nidx < 6048) {
                int p = nidx / 224, off = nidx % 224;
                nxt = *(const float4*)(pbase + (size_t)p * HW + off * 4);
            }
            // consume cur
            {
                int p = idx / 224, off = idx % 224;
                int c = p / 9, o = p % 9;
                int r = off / 56, jv = off % 56;
                float wrow = 0.0f;  // accumulate into lacc directly
                float pbo = spb[o];
                float pe[4] = {cur.x, cur.y, cur.z, cur.w};
                int cb = (c * 4 + r) * 4;
                int mb = r * 4;
                #pragma unroll
                for (int e = 0; e < 4; ++e) {
                    int li = (cb + e) * 56 + jv;
                    int bn = (int)sbinv[li];
                    float h = fmaf(spwT[bn * 9 + o], sminv[li], pbo * sinvv[li]);
                    float dd = pe[e] - h;
                    wrow = fmaf(smask[(mb + e) * 56 + jv] * dd, dd, wrow);
                }
                lacc += wrow;
            }
            cur = nxt;
            idx = nidx;
        }
        lacc *= (1.0f / 27.0f);
    }

    // -------- block reduction (8 waves) --------
    #pragma unroll
    for (int off = 32; off > 0; off >>= 1) {
        lacc += __shfl_down(lacc, off, 64);
        macc += __shfl_down(macc, off, 64);
    }
    __shared__ float red1[8], red2[8];
    int lane = tid & 63, wid = tid >> 6;
    if (lane == 0) { red1[wid] = lacc; red2[wid] = macc; }
    __syncthreads();
    if (tid == 0) {
        float l = 0.0f, m = 0.0f;
        #pragma unroll
        for (int w = 0; w < 8; ++w) { l += red1[w]; m += red2[w]; }
        pl[bid] = (double)l;
        pm[bid] = (double)m;
    }
}

__global__ void __launch_bounds__(256) finalize_kernel(
    const double* __restrict__ pl, const double* __restrict__ pm,
    float* __restrict__ out)
{
    double l = 0.0, m = 0.0;
    for (int idx = threadIdx.x; idx < NBLK_TOTAL; idx += 256) {
        l += pl[idx];
        m += pm[idx];
    }
    #pragma unroll
    for (int off = 32; off > 0; off >>= 1) {
        l += __shfl_down(l, off, 64);
        m += __shfl_down(m, off, 64);
    }
    __shared__ double sl[4], sm[4];
    int lane = threadIdx.x & 63, wid = threadIdx.x >> 6;
    if (lane == 0) { sl[wid] = l; sm[wid] = m; }
    __syncthreads();
    if (threadIdx.x == 0)
        out[0] = (float)((sl[0] + sl[1] + sl[2] + sl[3]) / (sm[0] + sm[1] + sm[2] + sm[3]));
}

extern "C" void kernel_launch(void* const* d_in, const int* in_sizes, int n_in,
                              void* d_out, int out_size, void* d_ws, size_t ws_size,
                              hipStream_t stream) {
    (void)in_sizes; (void)n_in; (void)out_size; (void)ws_size;
    const float* imgs = (const float*)d_in[0];
    const float* mask = (const float*)d_in[1];
    const float* pred[5];
    const float* pw[5];
    const float* pb[5];
    for (int k = 0; k < 5; ++k) {
        pred[k] = (const float*)d_in[2 + 3 * k];
        pw[k]   = (const float*)d_in[3 + 3 * k];
        pb[k]   = (const float*)d_in[4 + 3 * k];
    }
    double* pl = (double*)d_ws;
    double* pm = pl + NBLK_TOTAL;

    fused_kernel<<<NBLK_TOTAL, NTHR, 0, stream>>>(
        imgs, mask,
        pred[0], pred[1], pred[2], pred[3], pred[4],
        pw[0], pw[1], pw[2], pw[3], pw[4],
        pb[0], pb[1], pb[2], pb[3], pb[4],
        pl, pm);
    finalize_kernel<<<1, 256, 0, stream>>>(pl, pm, (float*)d_out);
}

// Round 15
// 64.262 us; speedup vs baseline: 1.7103x; 1.6365x over previous
//
#include <hip/hip_runtime.h>

#define N_IMG 32
#define H_IMG 224
#define W_IMG 224

// Fused grid, heavy scales first:
// S=16: [0, 25)        32*14*14 threads  (last block partial)
// S=8 : [25, 123)      32*28*28
// S=4 : [123, 515)     32*56*56
// S=2 : [515, 2083)    32*112*112
// S=1 : [2083, 5219)   32*224*112 vec2-threads (2 outputs each)
#define BS16_END 25
#define BS8_END 123
#define BS4_END 515
#define BS2_END 2083
#define NBLK_TOTAL 5219
#define S1_BLOCKS 3136          // 5219-2083, divisible by 8
#define S1_CHUNK  (S1_BLOCKS/8) // 392

__device__ __forceinline__ int reflect_idx(int i, int n) {
    if (i < 0) return -i;
    if (i >= n) return 2 * n - 2 - i;
    return i;
}

// bin = floor(atan2(gx,gy)/pi*9) mod 9 without atan2: direction-only sector count.
__device__ __forceinline__ int bin_from_g(float gx, float gy) {
    float u = gx * __builtin_copysignf(1.0f, gy);
    float w = __builtin_fabsf(gy);
    const float T[9] = {-5.6712818f, -1.7320508f, -0.83909963f, -0.36397023f,
                        0.0f, 0.36397023f, 0.83909963f, 1.7320508f, 5.6712818f};
    int c = 0;
    #pragma unroll
    for (int k = 0; k < 9; ++k) c += (u >= T[k] * w) ? 1 : 0;
    int b = c + 4;
    return (b >= 9) ? b - 9 : b;
}

// ---------------- s=1, two outputs per thread ----------------
__device__ __forceinline__ void s1_body2(int rel_bid,
    const float* __restrict__ imgs, const float* __restrict__ mask,
    const float* __restrict__ pred,
    const float* spwT, const float* spb, const float* sA, const float* sB,
    float Cc, float& local, float& mlocal)
{
    constexpr int WsV = W_IMG / 2;
    int vt = rel_bid * 256 + (int)threadIdx.x;
    int jv = vt % WsV;
    int t  = vt / WsV;
    int i  = t % H_IMG;
    int n  = t / H_IMG;
    int j0 = jv * 2;

    constexpr size_t cstride = (size_t)H_IMG * W_IMG;
    float2 mv = *(const float2*)(mask + (size_t)n * cstride + (size_t)i * W_IMG + j0);

    int y0 = reflect_idx(i - 1, H_IMG), y2 = reflect_idx(i + 1, H_IMG);
    int xl = reflect_idx(j0 - 1, W_IMG);
    int xr = reflect_idx(j0 + 2, W_IMG);

    float d2[2] = {0.0f, 0.0f};
    #pragma unroll
    for (int c = 0; c < 3; ++c) {
        const float* im = imgs + (size_t)(n * 3 + c) * cstride;
        const float* q0 = im + (size_t)y0 * W_IMG;
        const float* q1 = im + (size_t)i  * W_IMG;
        const float* q2 = im + (size_t)y2 * W_IMG;

        // img loads first (oldest in queue -> sobel waits only on these)
        float r0[4], r1[4], r2[4];
        float2 f;
        r0[0] = q0[xl]; f = *(const float2*)(q0 + j0); r0[1] = f.x; r0[2] = f.y; r0[3] = q0[xr];
        r1[0] = q1[xl]; f = *(const float2*)(q1 + j0); r1[1] = f.x; r1[2] = f.y; r1[3] = q1[xr];
        r2[0] = q2[xl]; f = *(const float2*)(q2 + j0); r2[1] = f.x; r2[2] = f.y; r2[3] = q2[xr];

        // stage 9 float2 preds (fly under the sobel math)
        const float* pr = pred + ((size_t)(n * 27 + c * 9) * H_IMG + i) * W_IMG + j0;
        float2 p[9];
        #pragma unroll
        for (int o = 0; o < 9; ++o) p[o] = *(const float2*)(pr + o * cstride);

        #pragma unroll
        for (int v = 0; v < 2; ++v) {
            float gx = (r0[v] - r0[v + 2]) + 2.0f * (r1[v] - r1[v + 2]) + (r2[v] - r2[v + 2]);
            float gy = (r0[v] - r2[v]) + 2.0f * (r0[v + 1] - r2[v + 1]) + (r0[v + 2] - r2[v + 2]);
            float mag = sqrtf(gx * gx + gy * gy);
            int bn = bin_from_g(gx, gy);
            float nrm2 = fmaf(mag, fmaf(mag, sA[bn], 2.0f * sB[bn]), Cc);
            float inv = 1.0f / fmaxf(sqrtf(nrm2), 1e-12f);
            #pragma unroll
            for (int o = 0; o < 9; ++o) {
                float h = fmaf(spwT[bn * 9 + o], mag, spb[o]) * inv;
                float pv = (v == 0) ? p[o].x : p[o].y;
                float dd = pv - h;
                d2[v] += dd * dd;
            }
        }
    }

    local  = (mv.x * d2[0] + mv.y * d2[1]) * (1.0f / 27.0f);
    mlocal = mv.x + mv.y;   // sum over s=1 == sum(mask)
}

// ---------------- generic S>=2, one output per thread ----------------
template <int S>
__device__ __forceinline__ void scale_body(int rel_bid,
    const float* __restrict__ imgs, const float* __restrict__ mask,
    const float* __restrict__ pred,
    const float* spwT, const float* spb, const float* sA, const float* sB,
    float Cc, float& local)
{
    constexpr int Hs = H_IMG / S, Ws = W_IMG / S;
    int vt = rel_bid * 256 + (int)threadIdx.x;
    if (vt >= N_IMG * Hs * Ws) return;
    int j = vt % Ws;
    int t = vt / Ws;
    int i = t % Hs;
    int n = t / Hs;

    // ---- mask pooling: fully unrolled, independent loads ----
    float M;
    const float* mbase = mask + (size_t)n * H_IMG * W_IMG + (size_t)(i * S) * W_IMG + j * S;
    if constexpr (S == 2) {
        float2 a = *(const float2*)(mbase);
        float2 b = *(const float2*)(mbase + W_IMG);
        M = (a.x + a.y + b.x + b.y) * 0.25f;
    } else {
        float msum = 0.0f;
        #pragma unroll
        for (int a = 0; a < S; ++a) {
            const float* mr = mbase + (size_t)a * W_IMG;
            #pragma unroll
            for (int q = 0; q < S / 4; ++q) {
                float4 fv = *(const float4*)(mr + q * 4);
                msum += (fv.x + fv.y) + (fv.z + fv.w);
            }
        }
        M = msum * (1.0f / (float)(S * S));
    }

    int y = i * S, x = j * S;
    int y0 = reflect_idx(y - 1, H_IMG), y2 = reflect_idx(y + 1, H_IMG);
    int x0 = reflect_idx(x - 1, W_IMG), x2 = reflect_idx(x + 1, W_IMG);
    constexpr size_t cstride = (size_t)Hs * Ws;

    float d2 = 0.0f;
    #pragma unroll
    for (int c = 0; c < 3; ++c) {
        const float* im = imgs + (size_t)(n * 3 + c) * H_IMG * W_IMG;
        const float* q0 = im + (size_t)y0 * W_IMG;
        const float* q1 = im + (size_t)y  * W_IMG;
        const float* q2 = im + (size_t)y2 * W_IMG;
        float p00 = q0[x0], p01 = q0[x], p02 = q0[x2];
        float p10 = q1[x0],             p12 = q1[x2];
        float p20 = q2[x0], p21 = q2[x], p22 = q2[x2];

        const float* pr = pred + ((size_t)(n * 27 + c * 9) * Hs + i) * Ws + j;
        float p[9];
        #pragma unroll
        for (int o = 0; o < 9; ++o) p[o] = pr[o * cstride];

        float gx = (p00 - p02) + 2.0f * (p10 - p12) + (p20 - p22);
        float gy = (p00 - p20) + 2.0f * (p01 - p21) + (p02 - p22);
        float mag = sqrtf(gx * gx + gy * gy);
        int bn = bin_from_g(gx, gy);
        float nrm2 = fmaf(mag, fmaf(mag, sA[bn], 2.0f * sB[bn]), Cc);
        float inv = 1.0f / fmaxf(sqrtf(nrm2), 1e-12f);

        #pragma unroll
        for (int o = 0; o < 9; ++o) {
            float h = fmaf(spwT[bn * 9 + o], mag, spb[o]) * inv;
            float dd = p[o] - h;
            d2 += dd * dd;
        }
    }

    local = M * d2 * (1.0f / 27.0f);
}

__global__ void __launch_bounds__(256) fused_kernel(
    const float* __restrict__ imgs, const float* __restrict__ mask,
    const float* __restrict__ pred0, const float* __restrict__ pred1,
    const float* __restrict__ pred2, const float* __restrict__ pred3,
    const float* __restrict__ pred4,
    const float* __restrict__ pw0, const float* __restrict__ pw1,
    const float* __restrict__ pw2, const float* __restrict__ pw3,
    const float* __restrict__ pw4,
    const float* __restrict__ pb0, const float* __restrict__ pb1,
    const float* __restrict__ pb2, const float* __restrict__ pb3,
    const float* __restrict__ pb4,
    double* __restrict__ pl, double* __restrict__ pm)
{
    __shared__ float spwT[81];   // spwT[b*9+o] = pw[o*9+b]
    __shared__ float spb[9];
    __shared__ float sA[9], sB[9], sC[1];

    int bid = blockIdx.x;
    const float* pw;  const float* pb;
    if (bid < BS16_END)      { pw = pw0; pb = pb0; }
    else if (bid < BS8_END)  { pw = pw1; pb = pb1; }
    else if (bid < BS4_END)  { pw = pw2; pb = pb2; }
    else if (bid < BS2_END)  { pw = pw3; pb = pb3; }
    else                     { pw = pw4; pb = pb4; }

    if (threadIdx.x < 81) {
        int o = threadIdx.x / 9, b = threadIdx.x % 9;
        spwT[b * 9 + o] = pw[threadIdx.x];
    }
    if (threadIdx.x < 9) spb[threadIdx.x] = pb[threadIdx.x];
    __syncthreads();
    if (threadIdx.x < 9) {
        float A = 0.0f, B = 0.0f;
        #pragma unroll
        for (int o = 0; o < 9; ++o) {
            float w = spwT[threadIdx.x * 9 + o];
            A += w * w;
            B += w * spb[o];
        }
        sA[threadIdx.x] = A;
        sB[threadIdx.x] = B;
        if (threadIdx.x == 0) {
            float Cc = 0.0f;
            #pragma unroll
            for (int o = 0; o < 9; ++o) Cc += spb[o] * spb[o];
            sC[0] = Cc;
        }
    }
    __syncthreads();
    float Cc = sC[0];

    float local = 0.0f, mlocal = 0.0f;
    if (bid < BS16_END)      scale_body<16>(bid,            imgs, mask, pred0, spwT, spb, sA, sB, Cc, local);
    else if (bid < BS8_END)  scale_body<8>(bid - BS16_END,  imgs, mask, pred1, spwT, spb, sA, sB, Cc, local);
    else if (bid < BS4_END)  scale_body<4>(bid - BS8_END,   imgs, mask, pred2, spwT, spb, sA, sB, Cc, local);
    else if (bid < BS2_END)  scale_body<2>(bid - BS4_END,   imgs, mask, pred3, spwT, spb, sA, sB, Cc, local);
    else {
        // bijective XCD chunk-swizzle: block b lands on XCD b%8; give each XCD
        // a contiguous work chunk so stencil-row/mask reuse is L2-local.
        int rel = bid - BS2_END;                    // 0..3135
        rel = (rel & 7) * S1_CHUNK + (rel >> 3);    // bijection on [0,3136)
        s1_body2(rel, imgs, mask, pred4, spwT, spb, sA, sB, Cc, local, mlocal);
    }

    #pragma unroll
    for (int off = 32; off > 0; off >>= 1) {
        local  += __shfl_down(local,  off, 64);
        mlocal += __shfl_down(mlocal, off, 64);
    }
    __shared__ float s1[4], s2[4];
    int lane = threadIdx.x & 63, wid = threadIdx.x >> 6;
    if (lane == 0) { s1[wid] = local; s2[wid] = mlocal; }
    __syncthreads();
    if (threadIdx.x == 0) {
        pl[bid] = (double)(s1[0] + s1[1] + s1[2] + s1[3]);
        pm[bid] = (double)(s2[0] + s2[1] + s2[2] + s2[3]);
    }
}

__global__ void __launch_bounds__(256) finalize_kernel(
    const double* __restrict__ pl, const double* __restrict__ pm,
    float* __restrict__ out)
{
    double l = 0.0, m = 0.0;
    for (int idx = threadIdx.x; idx < NBLK_TOTAL; idx += 256) {
        // per-scale weight w = s^2 (loss_k = s^2 * sum(M*d2/27) / sum(mask))
        double w = (idx < BS16_END) ? 256.0 : (idx < BS8_END) ? 64.0
                 : (idx < BS4_END) ? 16.0 : (idx < BS2_END) ? 4.0 : 1.0;
        l += w * pl[idx];
        m += pm[idx];   // nonzero only for s=1 blocks
    }
    #pragma unroll
    for (int off = 32; off > 0; off >>= 1) {
        l += __shfl_down(l, off, 64);
        m += __shfl_down(m, off, 64);
    }
    __shared__ double sl[4], sm[4];
    int lane = threadIdx.x & 63, wid = threadIdx.x >> 6;
    if (lane == 0) { sl[wid] = l; sm[wid] = m; }
    __syncthreads();
    if (threadIdx.x == 0)
        out[0] = (float)((sl[0] + sl[1] + sl[2] + sl[3]) / (sm[0] + sm[1] + sm[2] + sm[3]));
}

extern "C" void kernel_launch(void* const* d_in, const int* in_sizes, int n_in,
                              void* d_out, int out_size, void* d_ws, size_t ws_size,
                              hipStream_t stream) {
    (void)in_sizes; (void)n_in; (void)out_size; (void)ws_size;
    const float* imgs = (const float*)d_in[0];
    const float* mask = (const float*)d_in[1];
    const float* pred[5];
    const float* pw[5];
    const float* pb[5];
    for (int k = 0; k < 5; ++k) {
        pred[k] = (const float*)d_in[2 + 3 * k];
        pw[k]   = (const float*)d_in[3 + 3 * k];
        pb[k]   = (const float*)d_in[4 + 3 * k];
    }
    double* pl = (double*)d_ws;
    double* pm = pl + NBLK_TOTAL;

    fused_kernel<<<NBLK_TOTAL, 256, 0, stream>>>(
        imgs, mask,
        pred[0], pred[1], pred[2], pred[3], pred[4],
        pw[0], pw[1], pw[2], pw[3], pw[4],
        pb[0], pb[1], pb[2], pb[3], pb[4],
        pl, pm);
    finalize_kernel<<<1, 256, 0, stream>>>(pl, pm, (float*)d_out);
}